// Round 1
// baseline (711.014 us; speedup 1.0000x reference)
//
#include <hip/hip_runtime.h>

typedef unsigned short u16;
typedef __attribute__((ext_vector_type(4))) float floatx4;
typedef __attribute__((ext_vector_type(4))) unsigned int uintx4;
typedef __attribute__((ext_vector_type(8))) short short8;
typedef __attribute__((ext_vector_type(8))) __bf16 bf16x8;

#define B_SZ 8
#define C_LEN 2048
#define Q_LEN 512
#define D_DIM 1024
#define K4 (4 * D_DIM)

static __device__ __forceinline__ u16 f2bf(float f) {
    union { float f; unsigned int u; } v; v.f = f;
    unsigned int r = v.u + 0x7FFFu + ((v.u >> 16) & 1u);  // round-to-nearest-even
    return (u16)(r >> 16);
}
static __device__ __forceinline__ float bf2f(u16 h) {
    union { unsigned int u; float f; } v; v.u = ((unsigned int)h) << 16;
    return v.f;
}

// ---------- rowterm[b,c] = c . w_c ; colterm[b,q] = q . w_q ----------
__global__ void rowcol_kernel(const float* __restrict__ c, const float* __restrict__ q,
                              const float* __restrict__ w_c, const float* __restrict__ w_q,
                              float* __restrict__ rowterm, float* __restrict__ colterm) {
    int wid = blockIdx.x * 4 + (threadIdx.x >> 6);
    int lane = threadIdx.x & 63;
    const int NC = B_SZ * C_LEN;
    const int NQ = B_SZ * Q_LEN;
    const float* src; const float* w; float* dst;
    if (wid < NC) { src = c + (size_t)wid * D_DIM; w = w_c; dst = rowterm + wid; }
    else {
        int r = wid - NC; if (r >= NQ) return;
        src = q + (size_t)r * D_DIM; w = w_q; dst = colterm + r;
    }
    float s = 0.f;
    #pragma unroll
    for (int j = 0; j < 4; ++j) {
        int idx = j * 256 + lane * 4;
        floatx4 a = *(const floatx4*)(src + idx);
        floatx4 b = *(const floatx4*)(w + idx);
        s += a[0]*b[0] + a[1]*b[1] + a[2]*b[2] + a[3]*b[3];
    }
    for (int off = 32; off; off >>= 1) s += __shfl_down(s, off);
    if (lane == 0) *dst = s;
}

// ---------- qT[b,d,q] = bf16(q[b,q,d]) ----------
__global__ void transpose_q_kernel(const float* __restrict__ q, u16* __restrict__ qT) {
    __shared__ float tile[32][33];
    int b = blockIdx.z;
    int q0 = blockIdx.x * 32;
    int d0 = blockIdx.y * 32;
    int tx = threadIdx.x, ty = threadIdx.y;  // 32 x 8
    const float* qb = q + (size_t)b * Q_LEN * D_DIM;
    #pragma unroll
    for (int j = 0; j < 4; ++j) {
        int row = ty + j * 8;
        tile[row][tx] = qb[(size_t)(q0 + row) * D_DIM + d0 + tx];
    }
    __syncthreads();
    u16* qTb = qT + (size_t)b * D_DIM * Q_LEN;
    #pragma unroll
    for (int j = 0; j < 4; ++j) {
        int row = ty + j * 8;
        qTb[(size_t)(d0 + row) * Q_LEN + q0 + tx] = f2bf(tile[tx][row]);
    }
}

// ---------- generic 128x128 bf16 MFMA GEMM, C = A @ B^T (both operands K-major) ----------
// MODE 0: S' = (c .* w_cq) @ q^T            A: c fp32 (scale w_cq)  B: q fp32      out: S fp32
// MODE 1: c2q = P @ qT^T                    A: P bf16               B: qT bf16     out: c2q bf16
// MODE 2: z = X @ W_l^T + b_l               A: on-the-fly X bf16    B: W_l fp32    out: z fp32
template<int MODE>
__global__ __launch_bounds__(256) void mfma_gemm(
    const float* __restrict__ p0, const float* __restrict__ p1, const float* __restrict__ p2,
    const u16* __restrict__ u0, const u16* __restrict__ u1,
    float* __restrict__ of, u16* __restrict__ ob, const float* __restrict__ bias) {
    constexpr int KTOT = (MODE == 0) ? D_DIM : (MODE == 1) ? Q_LEN : K4;
    constexpr int LDO  = (MODE == 0) ? Q_LEN : D_DIM;
    __shared__ u16 As[128 * 32];
    __shared__ u16 Bs[128 * 32];
    const int tid = threadIdx.x;
    const int b  = blockIdx.z;
    const int n0 = blockIdx.x * 128;
    const int m0 = blockIdx.y * 128;

    const float* Afp = nullptr; const float* Bfp = nullptr;
    const u16* Abf = nullptr;   const u16* Bbf = nullptr;
    const float* scale = nullptr;
    const u16* Ac2q = nullptr;  const float* Aq2c = nullptr;
    if (MODE == 0) {
        Afp = p0 + (size_t)b * C_LEN * D_DIM;
        scale = p1;
        Bfp = p2 + (size_t)b * Q_LEN * D_DIM;
    } else if (MODE == 1) {
        Abf = u0 + (size_t)b * C_LEN * Q_LEN;
        Bbf = u1 + (size_t)b * D_DIM * Q_LEN;
    } else {
        Afp  = p0 + (size_t)b * C_LEN * D_DIM;   // c
        Ac2q = u0 + (size_t)b * C_LEN * D_DIM;   // c2q bf16
        Aq2c = p1 + (size_t)b * D_DIM;           // q2c
        Bfp  = p2;                                // W_l (shared across batch)
    }

    const int r  = tid >> 1;          // 0..127 staging row
    const int kh = (tid & 1) << 4;    // 0 or 16

    floatx4 acc[4][4];
    #pragma unroll
    for (int i = 0; i < 4; ++i)
        #pragma unroll
        for (int j = 0; j < 4; ++j)
            acc[i][j] = (floatx4)(0.0f);

    const int lane = tid & 63;
    const int wave = tid >> 6;
    const int wrow = (wave >> 1) * 64;
    const int wcol = (wave & 1) * 64;
    const int quad = lane >> 4;
    const int lrow = lane & 15;

    for (int k0 = 0; k0 < KTOT; k0 += 32) {
        union { u16 u[16]; short8 s[2]; uintx4 v[2]; } ta, tb;
        // ---- stage A ----
        if (MODE == 0) {
            const float* ap = Afp + (size_t)(m0 + r) * D_DIM + k0 + kh;
            const float* wp = scale + k0 + kh;
            #pragma unroll
            for (int v = 0; v < 4; ++v) {
                floatx4 cv = ((const floatx4*)ap)[v];
                floatx4 wv = ((const floatx4*)wp)[v];
                #pragma unroll
                for (int e = 0; e < 4; ++e) ta.u[v*4+e] = f2bf(cv[e] * wv[e]);
            }
        } else if (MODE == 1) {
            const uintx4* ap = (const uintx4*)(Abf + (size_t)(m0 + r) * Q_LEN + k0 + kh);
            ta.v[0] = ap[0]; ta.v[1] = ap[1];
        } else {
            const int kg  = k0 + kh;
            const int blk = kg >> 10;            // which of the 4 X-blocks
            const int kin = kg & (D_DIM - 1);
            if (blk == 0) {
                const float* ap = Afp + (size_t)(m0 + r) * D_DIM + kin;
                #pragma unroll
                for (int v = 0; v < 4; ++v) {
                    floatx4 cv = ((const floatx4*)ap)[v];
                    #pragma unroll
                    for (int e = 0; e < 4; ++e) ta.u[v*4+e] = f2bf(cv[e]);
                }
            } else if (blk == 1) {
                const uintx4* ap = (const uintx4*)(Ac2q + (size_t)(m0 + r) * D_DIM + kin);
                ta.v[0] = ap[0]; ta.v[1] = ap[1];
            } else if (blk == 2) {
                const float* ap = Afp + (size_t)(m0 + r) * D_DIM + kin;
                const u16*  cp = Ac2q + (size_t)(m0 + r) * D_DIM + kin;
                #pragma unroll
                for (int v = 0; v < 4; ++v) {
                    floatx4 cv = ((const floatx4*)ap)[v];
                    #pragma unroll
                    for (int e = 0; e < 4; ++e) ta.u[v*4+e] = f2bf(cv[e] * bf2f(cp[v*4+e]));
                }
            } else {
                const float* ap = Afp + (size_t)(m0 + r) * D_DIM + kin;
                const float* qp = Aq2c + kin;
                #pragma unroll
                for (int v = 0; v < 4; ++v) {
                    floatx4 cv = ((const floatx4*)ap)[v];
                    floatx4 qv = ((const floatx4*)qp)[v];
                    #pragma unroll
                    for (int e = 0; e < 4; ++e) ta.u[v*4+e] = f2bf(cv[e] * qv[e]);
                }
            }
        }
        // ---- stage B ----
        if (MODE == 0) {
            const float* bp = Bfp + (size_t)(n0 + r) * D_DIM + k0 + kh;
            #pragma unroll
            for (int v = 0; v < 4; ++v) {
                floatx4 bv = ((const floatx4*)bp)[v];
                #pragma unroll
                for (int e = 0; e < 4; ++e) tb.u[v*4+e] = f2bf(bv[e]);
            }
        } else if (MODE == 1) {
            const uintx4* bp = (const uintx4*)(Bbf + (size_t)(n0 + r) * Q_LEN + k0 + kh);
            tb.v[0] = bp[0]; tb.v[1] = bp[1];
        } else {
            const float* bp = Bfp + (size_t)(n0 + r) * K4 + k0 + kh;
            #pragma unroll
            for (int v = 0; v < 4; ++v) {
                floatx4 bv = ((const floatx4*)bp)[v];
                #pragma unroll
                for (int e = 0; e < 4; ++e) tb.u[v*4+e] = f2bf(bv[e]);
            }
        }
        short8* adst = (short8*)&As[r * 32 + kh];
        adst[0] = ta.s[0]; adst[1] = ta.s[1];
        short8* bdst = (short8*)&Bs[r * 32 + kh];
        bdst[0] = tb.s[0]; bdst[1] = tb.s[1];
        __syncthreads();
        // ---- compute: 2x2 waves, each 64x64 = 4x4 of 16x16x32 ----
        bf16x8 af[4], bfr[4];
        #pragma unroll
        for (int i = 0; i < 4; ++i)
            af[i] = __builtin_bit_cast(bf16x8, *(const short8*)&As[(wrow + i*16 + lrow) * 32 + quad * 8]);
        #pragma unroll
        for (int j = 0; j < 4; ++j)
            bfr[j] = __builtin_bit_cast(bf16x8, *(const short8*)&Bs[(wcol + j*16 + lrow) * 32 + quad * 8]);
        #pragma unroll
        for (int i = 0; i < 4; ++i)
            #pragma unroll
            for (int j = 0; j < 4; ++j)
                acc[i][j] = __builtin_amdgcn_mfma_f32_16x16x32_bf16(af[i], bfr[j], acc[i][j], 0, 0, 0);
        __syncthreads();
    }

    // ---- epilogue; C/D layout: col = lane&15, row = quad*4 + reg ----
    float* ofb = nullptr; u16* obb = nullptr;
    if (MODE == 0)      ofb = of + (size_t)b * C_LEN * Q_LEN;
    else if (MODE == 1) obb = ob + (size_t)b * C_LEN * D_DIM;
    else                ofb = of + (size_t)b * C_LEN * D_DIM;
    #pragma unroll
    for (int i = 0; i < 4; ++i) {
        #pragma unroll
        for (int j = 0; j < 4; ++j) {
            #pragma unroll
            for (int e = 0; e < 4; ++e) {
                int gm = m0 + wrow + i * 16 + quad * 4 + e;
                int gn = n0 + wcol + j * 16 + lrow;
                float v = acc[i][j][e];
                if (MODE == 0)      ofb[(size_t)gm * LDO + gn] = v;
                else if (MODE == 1) obb[(size_t)gm * LDO + gn] = f2bf(v);
                else                ofb[(size_t)gm * LDO + gn] = v + bias[gn];
            }
        }
    }
}

// ---------- softmax over Q per (b,c) row; also record rowmax ----------
__global__ void softmax_kernel(const float* __restrict__ S, const float* __restrict__ colterm,
                               u16* __restrict__ P, float* __restrict__ mbuf) {
    int row = blockIdx.x * 4 + (threadIdx.x >> 6);
    int lane = threadIdx.x & 63;
    int b = row >> 11;  // C_LEN = 2048
    const float* sp = S + (size_t)row * Q_LEN;
    const float* cp = colterm + (size_t)b * Q_LEN;
    float v[8];
    float m = -1e30f;
    #pragma unroll
    for (int j = 0; j < 8; ++j) {
        int idx = j * 64 + lane;
        v[j] = sp[idx] + cp[idx];
        m = fmaxf(m, v[j]);
    }
    for (int off = 32; off; off >>= 1) m = fmaxf(m, __shfl_xor(m, off));
    float s = 0.f;
    #pragma unroll
    for (int j = 0; j < 8; ++j) { v[j] = __expf(v[j] - m); s += v[j]; }
    for (int off = 32; off; off >>= 1) s += __shfl_xor(s, off);
    float inv = 1.0f / s;
    u16* pp = P + (size_t)row * Q_LEN;
    #pragma unroll
    for (int j = 0; j < 8; ++j) pp[j * 64 + lane] = f2bf(v[j] * inv);
    if (lane == 0) mbuf[row] = m;
}

// ---------- b_att[b,c] = softmax_c(rowmax + rowterm) ----------
__global__ __launch_bounds__(256) void batt_kernel(const float* __restrict__ mbuf,
                                                   const float* __restrict__ rowterm,
                                                   float* __restrict__ batt) {
    __shared__ float red[8];
    int b = blockIdx.x;
    int tid = threadIdx.x;
    const float* mb = mbuf + (size_t)b * C_LEN;
    const float* rt = rowterm + (size_t)b * C_LEN;
    float v[8];
    float m = -1e30f;
    #pragma unroll
    for (int j = 0; j < 8; ++j) { int idx = j * 256 + tid; v[j] = mb[idx] + rt[idx]; m = fmaxf(m, v[j]); }
    for (int off = 32; off; off >>= 1) m = fmaxf(m, __shfl_xor(m, off));
    int wave = tid >> 6, lane = tid & 63;
    if (lane == 0) red[wave] = m;
    __syncthreads();
    m = fmaxf(fmaxf(red[0], red[1]), fmaxf(red[2], red[3]));
    float s = 0.f;
    #pragma unroll
    for (int j = 0; j < 8; ++j) { v[j] = __expf(v[j] - m); s += v[j]; }
    for (int off = 32; off; off >>= 1) s += __shfl_xor(s, off);
    if (lane == 0) red[4 + wave] = s;
    __syncthreads();
    s = red[4] + red[5] + red[6] + red[7];
    float inv = 1.0f / s;
    float* bb = batt + (size_t)b * C_LEN;
    #pragma unroll
    for (int j = 0; j < 8; ++j) bb[j * 256 + tid] = v[j] * inv;
}

// ---------- q2c[b,d] = sum_c b_att[b,c] * c[b,c,d] (chunked + atomic) ----------
__global__ __launch_bounds__(256) void q2c_kernel(const float* __restrict__ batt,
                                                  const float* __restrict__ c,
                                                  float* __restrict__ q2c) {
    int d  = blockIdx.x * 256 + threadIdx.x;
    int b  = blockIdx.y;
    int c0 = blockIdx.z * 256;
    const float* cb = c + ((size_t)b * C_LEN + c0) * D_DIM + d;
    const float* bb = batt + (size_t)b * C_LEN + c0;
    float s = 0.f;
    #pragma unroll 4
    for (int i = 0; i < 256; ++i) s += bb[i] * cb[(size_t)i * D_DIM];
    atomicAdd(&q2c[(size_t)b * D_DIM + d], s);
}

extern "C" void kernel_launch(void* const* d_in, const int* in_sizes, int n_in,
                              void* d_out, int out_size, void* d_ws, size_t ws_size,
                              hipStream_t stream) {
    const float* c   = (const float*)d_in[0];
    const float* q   = (const float*)d_in[1];
    const float* wcq = (const float*)d_in[2];
    // b_cq (d_in[3]), b_c (d_in[5]), b_q (d_in[7]) cancel in both softmaxes — unused.
    const float* w_c = (const float*)d_in[4];
    const float* w_q = (const float*)d_in[6];
    const float* W_l = (const float*)d_in[8];
    const float* b_l = (const float*)d_in[9];
    float* out = (float*)d_out;

    char* ws = (char*)d_ws;
    float* S       = (float*)ws;                      // 33,554,432 B (B*C*Q fp32)
    u16*   c2q     = (u16*)ws;                        // aliases S (exactly B*C*D bf16) after softmax consumed S
    u16*   P       = (u16*)(ws + 33554432);           // 16,777,216 B
    u16*   qT      = (u16*)(ws + 50331648);           //  8,388,608 B
    float* rowterm = (float*)(ws + 58720256);         //     65,536 B
    float* colterm = (float*)(ws + 58785792);         //     16,384 B
    float* mbuf    = (float*)(ws + 58802176);         //     65,536 B
    float* batt    = (float*)(ws + 58867712);         //     65,536 B
    float* q2c     = (float*)(ws + 58933248);         //     32,768 B  (total ~59 MB)

    hipMemsetAsync(q2c, 0, B_SZ * D_DIM * sizeof(float), stream);
    rowcol_kernel<<<dim3(5120), dim3(256), 0, stream>>>(c, q, w_c, w_q, rowterm, colterm);
    transpose_q_kernel<<<dim3(16, 32, 8), dim3(32, 8), 0, stream>>>(q, qT);
    mfma_gemm<0><<<dim3(4, 16, 8), dim3(256), 0, stream>>>(c, wcq, q, nullptr, nullptr, S, nullptr, nullptr);
    softmax_kernel<<<dim3(4096), dim3(256), 0, stream>>>(S, colterm, P, mbuf);
    batt_kernel<<<dim3(8), dim3(256), 0, stream>>>(mbuf, rowterm, batt);
    q2c_kernel<<<dim3(4, 8, 8), dim3(256), 0, stream>>>(batt, c, q2c);
    mfma_gemm<1><<<dim3(8, 16, 8), dim3(256), 0, stream>>>(nullptr, nullptr, nullptr, P, qT, nullptr, c2q, nullptr);
    mfma_gemm<2><<<dim3(8, 16, 8), dim3(256), 0, stream>>>(c, q2c, W_l, c2q, nullptr, out, nullptr, b_l);
}

// Round 2
// 509.159 us; speedup vs baseline: 1.3964x; 1.3964x over previous
//
#include <hip/hip_runtime.h>

typedef unsigned short u16;
typedef __attribute__((ext_vector_type(4))) float floatx4;
typedef __attribute__((ext_vector_type(4))) unsigned short u16x4;
typedef __attribute__((ext_vector_type(4))) unsigned int uintx4;
typedef __attribute__((ext_vector_type(8))) short short8;
typedef __attribute__((ext_vector_type(8))) __bf16 bf16x8;

#define B_SZ 8
#define C_LEN 2048
#define Q_LEN 512
#define D_DIM 1024
#define K4 (4 * D_DIM)

static __device__ __forceinline__ u16 f2bf(float f) {
    union { float f; unsigned int u; } v; v.f = f;
    unsigned int r = v.u + 0x7FFFu + ((v.u >> 16) & 1u);  // round-to-nearest-even
    return (u16)(r >> 16);
}
static __device__ __forceinline__ float bf2f(u16 h) {
    union { unsigned int u; float f; } v; v.u = ((unsigned int)h) << 16;
    return v.f;
}

// async global->LDS, 16B per lane; LDS dest = wave-uniform base + lane*16
static __device__ __forceinline__ void async16(const void* g, void* l) {
    __builtin_amdgcn_global_load_lds(
        (const __attribute__((address_space(1))) unsigned int*)g,
        (__attribute__((address_space(3))) unsigned int*)(unsigned int)(unsigned long long)l,
        16, 0, 0);
}

// ---------- cbf = bf16(c); rowterm[b,c] = c . w_c ----------
__global__ __launch_bounds__(256) void precast_c(const float* __restrict__ c, const float* __restrict__ w_c,
                                                 u16* __restrict__ cbf, float* __restrict__ rowterm) {
    int row = blockIdx.x * 4 + (threadIdx.x >> 6);
    int lane = threadIdx.x & 63;
    const float* src = c + (size_t)row * D_DIM;
    u16* dst = cbf + (size_t)row * D_DIM;
    float s = 0.f;
    #pragma unroll
    for (int j = 0; j < 4; ++j) {
        int idx = j * 256 + lane * 4;
        floatx4 a = *(const floatx4*)(src + idx);
        floatx4 w = *(const floatx4*)(w_c + idx);
        s += a[0]*w[0] + a[1]*w[1] + a[2]*w[2] + a[3]*w[3];
        u16x4 o;
        #pragma unroll
        for (int e = 0; e < 4; ++e) o[e] = f2bf(a[e]);
        *(u16x4*)(dst + idx) = o;
    }
    for (int off = 32; off; off >>= 1) s += __shfl_down(s, off);
    if (lane == 0) rowterm[row] = s;
}

// ---------- qwbf = bf16(q .* w_cq); colterm[b,q] = q . w_q ----------
__global__ __launch_bounds__(256) void precast_q(const float* __restrict__ q, const float* __restrict__ w_cq,
                                                 const float* __restrict__ w_q,
                                                 u16* __restrict__ qwbf, float* __restrict__ colterm) {
    int row = blockIdx.x * 4 + (threadIdx.x >> 6);
    int lane = threadIdx.x & 63;
    const float* src = q + (size_t)row * D_DIM;
    u16* dst = qwbf + (size_t)row * D_DIM;
    float s = 0.f;
    #pragma unroll
    for (int j = 0; j < 4; ++j) {
        int idx = j * 256 + lane * 4;
        floatx4 a  = *(const floatx4*)(src + idx);
        floatx4 wc = *(const floatx4*)(w_cq + idx);
        floatx4 wq = *(const floatx4*)(w_q + idx);
        s += a[0]*wq[0] + a[1]*wq[1] + a[2]*wq[2] + a[3]*wq[3];
        u16x4 o;
        #pragma unroll
        for (int e = 0; e < 4; ++e) o[e] = f2bf(a[e] * wc[e]);
        *(u16x4*)(dst + idx) = o;
    }
    for (int off = 32; off; off >>= 1) s += __shfl_down(s, off);
    if (lane == 0) colterm[row] = s;
}

// ---------- Wbf = bf16(W_l) ----------
__global__ __launch_bounds__(256) void precast_W(const float* __restrict__ W, u16* __restrict__ Wbf) {
    int i = (blockIdx.x * 256 + threadIdx.x) * 4;
    floatx4 v = *(const floatx4*)(W + i);
    u16x4 o;
    #pragma unroll
    for (int e = 0; e < 4; ++e) o[e] = f2bf(v[e]);
    *(u16x4*)(Wbf + i) = o;
}

// ---------- qT[b,d,q] = bf16(q[b,q,d]) ----------
__global__ void transpose_q_kernel(const float* __restrict__ q, u16* __restrict__ qT) {
    __shared__ float tile[32][33];
    int b = blockIdx.z;
    int q0 = blockIdx.x * 32;
    int d0 = blockIdx.y * 32;
    int tx = threadIdx.x, ty = threadIdx.y;  // 32 x 8
    const float* qb = q + (size_t)b * Q_LEN * D_DIM;
    #pragma unroll
    for (int j = 0; j < 4; ++j) {
        int row = ty + j * 8;
        tile[row][tx] = qb[(size_t)(q0 + row) * D_DIM + d0 + tx];
    }
    __syncthreads();
    u16* qTb = qT + (size_t)b * D_DIM * Q_LEN;
    #pragma unroll
    for (int j = 0; j < 4; ++j) {
        int row = ty + j * 8;
        qTb[(size_t)(d0 + row) * Q_LEN + q0 + tx] = f2bf(tile[tx][row]);
    }
}

// ---------- unified async bf16 GEMM, C = A @ B^T, 128x128 tile, BK=32 ----------
// MODE 0: S  = cbf @ qwbf^T             out fp32 [2048,512]
// MODE 1: c2q = P @ qT^T                out bf16 [2048,1024]
// MODE 2: z  = X @ [Wbf|Wq]^T + b_l     A per-k-block {cbf,c2q,cc2q,cbf}, out fp32
template<int MODE>
__global__ __launch_bounds__(256) void gemm_async(
    const u16* __restrict__ A0, const u16* __restrict__ A1, const u16* __restrict__ A2,
    const u16* __restrict__ B0, const u16* __restrict__ B1,
    float* __restrict__ of, u16* __restrict__ ob, const float* __restrict__ bias) {
    constexpr int KTOT = (MODE == 0) ? 1024 : (MODE == 1) ? 512 : 4096;
    constexpr int LDA  = (MODE == 1) ? 512 : 1024;
    constexpr int LDB  = (MODE == 0) ? 1024 : (MODE == 1) ? 512 : 4096;
    constexpr int LDO  = (MODE == 0) ? 512 : 1024;
    __shared__ u16 As[128 * 32];
    __shared__ u16 Bs[128 * 32];
    const int tid  = threadIdx.x;
    const int lane = tid & 63;
    const int wave = tid >> 6;
    const int b    = blockIdx.z;
    const int n0   = blockIdx.x * 128;
    const int m0   = blockIdx.y * 128;

    const u16* Aab0 = nullptr; const u16* Aab1 = nullptr; const u16* Aab2 = nullptr;
    const u16* Ab = nullptr; const u16* Bb = nullptr; const u16* Bqb = nullptr;
    if (MODE == 0)      { Ab = A0 + (size_t)b * C_LEN * D_DIM; Bb = B0 + (size_t)b * Q_LEN * D_DIM; }
    else if (MODE == 1) { Ab = A0 + (size_t)b * C_LEN * Q_LEN; Bb = B0 + (size_t)b * D_DIM * Q_LEN; }
    else {
        Aab0 = A0 + (size_t)b * C_LEN * D_DIM;
        Aab1 = A1 + (size_t)b * C_LEN * D_DIM;
        Aab2 = A2 + (size_t)b * C_LEN * D_DIM;
        Bb   = B0;                                  // Wbf, shared across batch
        Bqb  = B1 + (size_t)b * D_DIM * D_DIM;      // Wq
    }

    const int srow = lane >> 2;          // 0..15
    const int scol = (lane & 3) * 8;     // 0,8,16,24
    const int ca   = wave * 2;           // this wave's first 16-row chunk

    floatx4 acc[4][4];
    #pragma unroll
    for (int i = 0; i < 4; ++i)
        #pragma unroll
        for (int j = 0; j < 4; ++j)
            acc[i][j] = (floatx4)(0.0f);

    const int wrow = (wave >> 1) * 64;
    const int wcol = (wave & 1) * 64;
    const int quad = lane >> 4;
    const int lrow = lane & 15;

    for (int k0 = 0; k0 < KTOT; k0 += 32) {
        // ---- stage A (async, 2 chunks of 16 rows per wave) ----
        #pragma unroll
        for (int cc = 0; cc < 2; ++cc) {
            int chunk = ca + cc;
            int row = m0 + chunk * 16 + srow;
            const u16* src;
            if (MODE == 2) {
                int blk = k0 >> 10;
                const u16* base = (blk == 1) ? Aab1 : ((blk == 2) ? Aab2 : Aab0);
                src = base + (size_t)row * 1024 + (k0 & 1023) + scol;
            } else {
                src = Ab + (size_t)row * LDA + k0 + scol;
            }
            async16(src, &As[chunk * 512]);
        }
        // ---- stage B ----
        #pragma unroll
        for (int cc = 0; cc < 2; ++cc) {
            int chunk = ca + cc;
            int row = n0 + chunk * 16 + srow;
            const u16* src;
            if (MODE == 2 && k0 >= 3072) {
                src = Bqb + (size_t)row * 1024 + (k0 - 3072) + scol;
            } else {
                src = Bb + (size_t)row * LDB + k0 + scol;
            }
            async16(src, &Bs[chunk * 512]);
        }
        __syncthreads();
        // ---- compute: 2x2 waves, each 64x64 = 4x4 of 16x16x32 ----
        bf16x8 af[4], bfr[4];
        #pragma unroll
        for (int i = 0; i < 4; ++i)
            af[i] = __builtin_bit_cast(bf16x8, *(const short8*)&As[(wrow + i*16 + lrow) * 32 + quad * 8]);
        #pragma unroll
        for (int j = 0; j < 4; ++j)
            bfr[j] = __builtin_bit_cast(bf16x8, *(const short8*)&Bs[(wcol + j*16 + lrow) * 32 + quad * 8]);
        #pragma unroll
        for (int i = 0; i < 4; ++i)
            #pragma unroll
            for (int j = 0; j < 4; ++j)
                acc[i][j] = __builtin_amdgcn_mfma_f32_16x16x32_bf16(af[i], bfr[j], acc[i][j], 0, 0, 0);
        __syncthreads();
    }

    // ---- epilogue; C/D layout: col = lane&15, row = quad*4 + reg ----
    float* ofb = nullptr; u16* obb = nullptr;
    if (MODE == 0)      ofb = of + (size_t)b * C_LEN * Q_LEN;
    else if (MODE == 1) obb = ob + (size_t)b * C_LEN * D_DIM;
    else                ofb = of + (size_t)b * C_LEN * D_DIM;
    #pragma unroll
    for (int i = 0; i < 4; ++i) {
        #pragma unroll
        for (int j = 0; j < 4; ++j) {
            #pragma unroll
            for (int e = 0; e < 4; ++e) {
                int gm = m0 + wrow + i * 16 + quad * 4 + e;
                int gn = n0 + wcol + j * 16 + lrow;
                float v = acc[i][j][e];
                if (MODE == 0)      ofb[(size_t)gm * LDO + gn] = v;
                else if (MODE == 1) obb[(size_t)gm * LDO + gn] = f2bf(v);
                else                ofb[(size_t)gm * LDO + gn] = v + bias[gn];
            }
        }
    }
}

// ---------- softmax over Q per (b,c) row; also record rowmax ----------
__global__ void softmax_kernel(const float* __restrict__ S, const float* __restrict__ colterm,
                               u16* __restrict__ P, float* __restrict__ mbuf) {
    int row = blockIdx.x * 4 + (threadIdx.x >> 6);
    int lane = threadIdx.x & 63;
    int b = row >> 11;  // C_LEN = 2048
    const float* sp = S + (size_t)row * Q_LEN;
    const float* cp = colterm + (size_t)b * Q_LEN;
    float v[8];
    float m = -1e30f;
    #pragma unroll
    for (int j = 0; j < 8; ++j) {
        int idx = j * 64 + lane;
        v[j] = sp[idx] + cp[idx];
        m = fmaxf(m, v[j]);
    }
    for (int off = 32; off; off >>= 1) m = fmaxf(m, __shfl_xor(m, off));
    float s = 0.f;
    #pragma unroll
    for (int j = 0; j < 8; ++j) { v[j] = __expf(v[j] - m); s += v[j]; }
    for (int off = 32; off; off >>= 1) s += __shfl_xor(s, off);
    float inv = 1.0f / s;
    u16* pp = P + (size_t)row * Q_LEN;
    #pragma unroll
    for (int j = 0; j < 8; ++j) pp[j * 64 + lane] = f2bf(v[j] * inv);
    if (lane == 0) mbuf[row] = m;
}

// ---------- b_att[b,c] = softmax_c(rowmax + rowterm) ----------
__global__ __launch_bounds__(256) void batt_kernel(const float* __restrict__ mbuf,
                                                   const float* __restrict__ rowterm,
                                                   float* __restrict__ batt) {
    __shared__ float red[8];
    int b = blockIdx.x;
    int tid = threadIdx.x;
    const float* mb = mbuf + (size_t)b * C_LEN;
    const float* rt = rowterm + (size_t)b * C_LEN;
    float v[8];
    float m = -1e30f;
    #pragma unroll
    for (int j = 0; j < 8; ++j) { int idx = j * 256 + tid; v[j] = mb[idx] + rt[idx]; m = fmaxf(m, v[j]); }
    for (int off = 32; off; off >>= 1) m = fmaxf(m, __shfl_xor(m, off));
    int wave = tid >> 6, lane = tid & 63;
    if (lane == 0) red[wave] = m;
    __syncthreads();
    m = fmaxf(fmaxf(red[0], red[1]), fmaxf(red[2], red[3]));
    float s = 0.f;
    #pragma unroll
    for (int j = 0; j < 8; ++j) { v[j] = __expf(v[j] - m); s += v[j]; }
    for (int off = 32; off; off >>= 1) s += __shfl_xor(s, off);
    if (lane == 0) red[4 + wave] = s;
    __syncthreads();
    s = red[4] + red[5] + red[6] + red[7];
    float inv = 1.0f / s;
    float* bb = batt + (size_t)b * C_LEN;
    #pragma unroll
    for (int j = 0; j < 8; ++j) bb[j * 256 + tid] = v[j] * inv;
}

// ---------- q2c[b,d] = sum_c b_att[b,c] * c[b,c,d] (chunked + atomic) ----------
__global__ __launch_bounds__(256) void q2c_kernel(const float* __restrict__ batt,
                                                  const float* __restrict__ c,
                                                  float* __restrict__ q2c) {
    int d  = blockIdx.x * 256 + threadIdx.x;
    int b  = blockIdx.y;
    int c0 = blockIdx.z * 256;
    const float* cb = c + ((size_t)b * C_LEN + c0) * D_DIM + d;
    const float* bb = batt + (size_t)b * C_LEN + c0;
    float s = 0.f;
    #pragma unroll 4
    for (int i = 0; i < 256; ++i) s += bb[i] * cb[(size_t)i * D_DIM];
    atomicAdd(&q2c[(size_t)b * D_DIM + d], s);
}

// ---------- cc2q = bf16(cbf * c2q) ----------
__global__ __launch_bounds__(256) void cc2q_kernel(const u16* __restrict__ cbf, const u16* __restrict__ c2q,
                                                   u16* __restrict__ cc2q) {
    int i = (blockIdx.x * 256 + threadIdx.x) * 4;
    u16x4 a = *(const u16x4*)(cbf + i);
    u16x4 c = *(const u16x4*)(c2q + i);
    u16x4 o;
    #pragma unroll
    for (int e = 0; e < 4; ++e) o[e] = f2bf(bf2f(a[e]) * bf2f(c[e]));
    *(u16x4*)(cc2q + i) = o;
}

// ---------- Wq[b,n,k] = bf16(W_l[n, 3072+k] * q2c[b,k]) ----------
__global__ __launch_bounds__(256) void wq_kernel(const float* __restrict__ W, const float* __restrict__ q2c,
                                                 u16* __restrict__ Wq) {
    int b = blockIdx.y;
    int i = (blockIdx.x * 256 + threadIdx.x) * 4;   // [0, 1M)
    int n = i >> 10, k = i & 1023;
    floatx4 w = *(const floatx4*)(W + (size_t)n * K4 + 3072 + k);
    floatx4 g = *(const floatx4*)(q2c + (size_t)b * D_DIM + k);
    u16x4 o;
    #pragma unroll
    for (int e = 0; e < 4; ++e) o[e] = f2bf(w[e] * g[e]);
    *(u16x4*)(Wq + (size_t)b * 1048576 + i) = o;
}

extern "C" void kernel_launch(void* const* d_in, const int* in_sizes, int n_in,
                              void* d_out, int out_size, void* d_ws, size_t ws_size,
                              hipStream_t stream) {
    const float* c   = (const float*)d_in[0];
    const float* q   = (const float*)d_in[1];
    const float* wcq = (const float*)d_in[2];
    // b_cq (d_in[3]), b_c (d_in[5]), b_q (d_in[7]) cancel in both softmaxes — unused.
    const float* w_c = (const float*)d_in[4];
    const float* w_q = (const float*)d_in[6];
    const float* W_l = (const float*)d_in[8];
    const float* b_l = (const float*)d_in[9];
    float* out = (float*)d_out;

    char* ws = (char*)d_ws;
    u16*   cbf     = (u16*)ws;                        // 32 MB @ 0
    float* S       = (float*)(ws + 33554432);         // 32 MB fp32 @ 32M
    u16*   c2q     = (u16*)(ws + 33554432);           // aliases S (bf16, 32 MB) after softmax
    u16*   qwbf    = (u16*)(ws + 67108864);           //  8 MB @ 64M
    u16*   qT      = (u16*)(ws + 75497472);           //  8 MB @ 72M
    u16*   P       = (u16*)(ws + 83886080);           // 16 MB @ 80M
    u16*   cc2q    = (u16*)(ws + 67108864);           // 32 MB, aliases qwbf+qT+P (all dead by then)
    u16*   Wbf     = (u16*)(ws + 100663296);          //  8 MB @ 96M
    u16*   Wq      = (u16*)(ws + 109051904);          // 16 MB @ 104M
    float* rowterm = (float*)(ws + 125829120);        // 64 KB
    float* colterm = (float*)(ws + 125894656);        // 16 KB
    float* mbuf    = (float*)(ws + 125911040);        // 64 KB
    float* batt    = (float*)(ws + 125976576);        // 64 KB
    float* q2c     = (float*)(ws + 126042112);        // 32 KB   (total ~120.3 MB)

    hipMemsetAsync(q2c, 0, B_SZ * D_DIM * sizeof(float), stream);
    precast_c<<<dim3(4096), dim3(256), 0, stream>>>(c, w_c, cbf, rowterm);
    precast_q<<<dim3(1024), dim3(256), 0, stream>>>(q, wcq, w_q, qwbf, colterm);
    transpose_q_kernel<<<dim3(16, 32, 8), dim3(32, 8), 0, stream>>>(q, qT);
    precast_W<<<dim3(4096), dim3(256), 0, stream>>>(W_l, Wbf);
    gemm_async<0><<<dim3(4, 16, 8), dim3(256), 0, stream>>>(cbf, nullptr, nullptr, qwbf, nullptr, S, nullptr, nullptr);
    softmax_kernel<<<dim3(4096), dim3(256), 0, stream>>>(S, colterm, P, mbuf);
    batt_kernel<<<dim3(8), dim3(256), 0, stream>>>(mbuf, rowterm, batt);
    q2c_kernel<<<dim3(4, 8, 8), dim3(256), 0, stream>>>(batt, c, q2c);
    gemm_async<1><<<dim3(8, 16, 8), dim3(256), 0, stream>>>(P, nullptr, nullptr, qT, nullptr, nullptr, c2q, nullptr);
    cc2q_kernel<<<dim3(16384), dim3(256), 0, stream>>>(cbf, c2q, cc2q);
    wq_kernel<<<dim3(1024, 8), dim3(256), 0, stream>>>(W_l, q2c, Wq);
    gemm_async<2><<<dim3(8, 16, 8), dim3(256), 0, stream>>>(cbf, c2q, cc2q, Wbf, Wq, out, nullptr, b_l);
}

// Round 3
// 436.181 us; speedup vs baseline: 1.6301x; 1.1673x over previous
//
#include <hip/hip_runtime.h>

typedef unsigned short u16;
typedef __attribute__((ext_vector_type(4))) float floatx4;
typedef __attribute__((ext_vector_type(4))) unsigned short u16x4;
typedef __attribute__((ext_vector_type(8))) short short8;
typedef __attribute__((ext_vector_type(8))) __bf16 bf16x8;

#define B_SZ 8
#define C_LEN 2048
#define Q_LEN 512
#define D_DIM 1024
#define K4 (4 * D_DIM)

static __device__ __forceinline__ u16 f2bf(float f) {
    union { float f; unsigned int u; } v; v.f = f;
    unsigned int r = v.u + 0x7FFFu + ((v.u >> 16) & 1u);  // round-to-nearest-even
    return (u16)(r >> 16);
}
static __device__ __forceinline__ float bf2f(u16 h) {
    union { unsigned int u; float f; } v; v.u = ((unsigned int)h) << 16;
    return v.f;
}

// async global->LDS, 16B per lane; LDS dest = wave-uniform base + lane*16
static __device__ __forceinline__ void async16(const void* g, void* l) {
    __builtin_amdgcn_global_load_lds(
        (const __attribute__((address_space(1))) unsigned int*)g,
        (__attribute__((address_space(3))) unsigned int*)(unsigned int)(unsigned long long)l,
        16, 0, 0);
}

// ---------- cbf = bf16(c); rowterm[b,c] = c . w_c ----------
__global__ __launch_bounds__(256) void precast_c(const float* __restrict__ c, const float* __restrict__ w_c,
                                                 u16* __restrict__ cbf, float* __restrict__ rowterm) {
    int row = blockIdx.x * 4 + (threadIdx.x >> 6);
    int lane = threadIdx.x & 63;
    const float* src = c + (size_t)row * D_DIM;
    u16* dst = cbf + (size_t)row * D_DIM;
    float s = 0.f;
    #pragma unroll
    for (int j = 0; j < 4; ++j) {
        int idx = j * 256 + lane * 4;
        floatx4 a = *(const floatx4*)(src + idx);
        floatx4 w = *(const floatx4*)(w_c + idx);
        s += a[0]*w[0] + a[1]*w[1] + a[2]*w[2] + a[3]*w[3];
        u16x4 o;
        #pragma unroll
        for (int e = 0; e < 4; ++e) o[e] = f2bf(a[e]);
        *(u16x4*)(dst + idx) = o;
    }
    for (int off = 32; off; off >>= 1) s += __shfl_down(s, off);
    if (lane == 0) rowterm[row] = s;
}

// ---------- qwbf = bf16(q .* w_cq); colterm[b,q] = q . w_q ----------
__global__ __launch_bounds__(256) void precast_q(const float* __restrict__ q, const float* __restrict__ w_cq,
                                                 const float* __restrict__ w_q,
                                                 u16* __restrict__ qwbf, float* __restrict__ colterm) {
    int row = blockIdx.x * 4 + (threadIdx.x >> 6);
    int lane = threadIdx.x & 63;
    const float* src = q + (size_t)row * D_DIM;
    u16* dst = qwbf + (size_t)row * D_DIM;
    float s = 0.f;
    #pragma unroll
    for (int j = 0; j < 4; ++j) {
        int idx = j * 256 + lane * 4;
        floatx4 a  = *(const floatx4*)(src + idx);
        floatx4 wc = *(const floatx4*)(w_cq + idx);
        floatx4 wq = *(const floatx4*)(w_q + idx);
        s += a[0]*wq[0] + a[1]*wq[1] + a[2]*wq[2] + a[3]*wq[3];
        u16x4 o;
        #pragma unroll
        for (int e = 0; e < 4; ++e) o[e] = f2bf(a[e] * wc[e]);
        *(u16x4*)(dst + idx) = o;
    }
    for (int off = 32; off; off >>= 1) s += __shfl_down(s, off);
    if (lane == 0) colterm[row] = s;
}

// ---------- Wbf middle columns only: bf16(W_l[:, 1024:3072]) ----------
__global__ __launch_bounds__(256) void precast_W(const float* __restrict__ W, u16* __restrict__ Wbf) {
    int t = blockIdx.x * 256 + threadIdx.x;
    int e4 = t * 4;                    // [0, 2M)
    int n = e4 >> 11;                  // row
    int k = 1024 + (e4 & 2047);        // col in [1024, 3072)
    floatx4 v = *(const floatx4*)(W + (size_t)n * K4 + k);
    u16x4 o;
    #pragma unroll
    for (int e = 0; e < 4; ++e) o[e] = f2bf(v[e]);
    *(u16x4*)(Wbf + (size_t)n * K4 + k) = o;
}

// ---------- qT[b,d,q] = bf16(q[b,q,d]) ----------
__global__ void transpose_q_kernel(const float* __restrict__ q, u16* __restrict__ qT) {
    __shared__ float tile[32][33];
    int b = blockIdx.z;
    int q0 = blockIdx.x * 32;
    int d0 = blockIdx.y * 32;
    int tx = threadIdx.x, ty = threadIdx.y;  // 32 x 8
    const float* qb = q + (size_t)b * Q_LEN * D_DIM;
    #pragma unroll
    for (int j = 0; j < 4; ++j) {
        int row = ty + j * 8;
        tile[row][tx] = qb[(size_t)(q0 + row) * D_DIM + d0 + tx];
    }
    __syncthreads();
    u16* qTb = qT + (size_t)b * D_DIM * Q_LEN;
    #pragma unroll
    for (int j = 0; j < 4; ++j) {
        int row = ty + j * 8;
        qTb[(size_t)(d0 + row) * Q_LEN + q0 + tx] = f2bf(tile[tx][row]);
    }
}

// ---------- unified async bf16 GEMM, C = A @ B^T, 128x128 tile, BK=32 ----------
// MODE 0: S   = cbf @ qwbf^T              out fp32 [2048,512]
// MODE 1: c2q = P @ qT^T                  out bf16 [2048,1024]
// MODE 2: z   = sum of 3 clean K-sections (cbf@Wm^T + c2q@W2^T + cc2q@W3^T) + b_l
template<int MODE>
__global__ __launch_bounds__(256) void gemm_async(
    const u16* __restrict__ A0, const u16* __restrict__ A1, const u16* __restrict__ A2,
    const u16* __restrict__ B0, const u16* __restrict__ B1,
    float* __restrict__ of, u16* __restrict__ ob, const float* __restrict__ bias) {
    constexpr int NSEC = (MODE == 2) ? 3 : 1;
    constexpr int KSEC = (MODE == 1) ? 512 : 1024;
    constexpr int LDA  = (MODE == 1) ? 512 : 1024;
    constexpr int LDO  = (MODE == 0) ? 512 : 1024;
    __shared__ u16 As[128 * 32];
    __shared__ u16 Bs[128 * 32];
    const int tid  = threadIdx.x;
    const int lane = tid & 63;
    const int wave = tid >> 6;
    const int b    = blockIdx.z;
    const int n0   = blockIdx.x * 128;
    const int m0   = blockIdx.y * 128;

    const u16* Aarr[NSEC];
    const u16* Barr[NSEC];
    int ldbs[NSEC];
    if constexpr (MODE == 0) {
        Aarr[0] = A0 + (size_t)b * C_LEN * D_DIM; Barr[0] = B0 + (size_t)b * Q_LEN * D_DIM; ldbs[0] = 1024;
    } else if constexpr (MODE == 1) {
        Aarr[0] = A0 + (size_t)b * C_LEN * Q_LEN; Barr[0] = B0 + (size_t)b * D_DIM * Q_LEN; ldbs[0] = 512;
    } else {
        Aarr[0] = A0 + (size_t)b * C_LEN * D_DIM; Barr[0] = B0 + (size_t)b * D_DIM * D_DIM; ldbs[0] = 1024;
        Aarr[1] = A1 + (size_t)b * C_LEN * D_DIM; Barr[1] = B1 + 1024;                      ldbs[1] = 4096;
        Aarr[2] = A2 + (size_t)b * C_LEN * D_DIM; Barr[2] = B1 + 2048;                      ldbs[2] = 4096;
    }

    const int srow = lane >> 2;          // 0..15
    const int scol = (lane & 3) * 8;     // 0,8,16,24
    const int ca   = wave * 2;           // this wave's first 16-row chunk

    floatx4 acc[4][4];
    #pragma unroll
    for (int i = 0; i < 4; ++i)
        #pragma unroll
        for (int j = 0; j < 4; ++j)
            acc[i][j] = (floatx4)(0.0f);

    const int wrow = (wave >> 1) * 64;
    const int wcol = (wave & 1) * 64;
    const int quad = lane >> 4;
    const int lrow = lane & 15;

    #pragma unroll
    for (int sec = 0; sec < NSEC; ++sec) {
        const u16* __restrict__ Ab = Aarr[sec];
        const u16* __restrict__ Bb = Barr[sec];
        const int LB = ldbs[sec];
        for (int k0 = 0; k0 < KSEC; k0 += 32) {
            #pragma unroll
            for (int cc = 0; cc < 2; ++cc) {
                int chunk = ca + cc;
                async16(Ab + (size_t)(m0 + chunk * 16 + srow) * LDA + k0 + scol, &As[chunk * 512]);
            }
            #pragma unroll
            for (int cc = 0; cc < 2; ++cc) {
                int chunk = ca + cc;
                async16(Bb + (size_t)(n0 + chunk * 16 + srow) * LB + k0 + scol, &Bs[chunk * 512]);
            }
            __syncthreads();
            bf16x8 af[4], bfr[4];
            #pragma unroll
            for (int i = 0; i < 4; ++i)
                af[i] = __builtin_bit_cast(bf16x8, *(const short8*)&As[(wrow + i*16 + lrow) * 32 + quad * 8]);
            #pragma unroll
            for (int j = 0; j < 4; ++j)
                bfr[j] = __builtin_bit_cast(bf16x8, *(const short8*)&Bs[(wcol + j*16 + lrow) * 32 + quad * 8]);
            #pragma unroll
            for (int i = 0; i < 4; ++i)
                #pragma unroll
                for (int j = 0; j < 4; ++j)
                    acc[i][j] = __builtin_amdgcn_mfma_f32_16x16x32_bf16(af[i], bfr[j], acc[i][j], 0, 0, 0);
            __syncthreads();
        }
    }

    // ---- epilogue; C/D layout: col = lane&15, row = quad*4 + reg ----
    float* ofb = nullptr; u16* obb = nullptr;
    if (MODE == 0)      ofb = of + (size_t)b * C_LEN * Q_LEN;
    else if (MODE == 1) obb = ob + (size_t)b * C_LEN * D_DIM;
    else                ofb = of + (size_t)b * C_LEN * D_DIM;
    #pragma unroll
    for (int i = 0; i < 4; ++i) {
        #pragma unroll
        for (int j = 0; j < 4; ++j) {
            #pragma unroll
            for (int e = 0; e < 4; ++e) {
                int gm = m0 + wrow + i * 16 + quad * 4 + e;
                int gn = n0 + wcol + j * 16 + lrow;
                float v = acc[i][j][e];
                if (MODE == 0)      ofb[(size_t)gm * LDO + gn] = v;
                else if (MODE == 1) obb[(size_t)gm * LDO + gn] = f2bf(v);
                else                ofb[(size_t)gm * LDO + gn] = v + bias[gn];
            }
        }
    }
}

// ---------- softmax over Q per (b,c) row; also record rowmax ----------
__global__ void softmax_kernel(const float* __restrict__ S, const float* __restrict__ colterm,
                               u16* __restrict__ P, float* __restrict__ mbuf) {
    int row = blockIdx.x * 4 + (threadIdx.x >> 6);
    int lane = threadIdx.x & 63;
    int b = row >> 11;  // C_LEN = 2048
    const float* sp = S + (size_t)row * Q_LEN;
    const float* cp = colterm + (size_t)b * Q_LEN;
    float v[8];
    float m = -1e30f;
    #pragma unroll
    for (int j = 0; j < 8; ++j) {
        int idx = j * 64 + lane;
        v[j] = sp[idx] + cp[idx];
        m = fmaxf(m, v[j]);
    }
    for (int off = 32; off; off >>= 1) m = fmaxf(m, __shfl_xor(m, off));
    float s = 0.f;
    #pragma unroll
    for (int j = 0; j < 8; ++j) { v[j] = __expf(v[j] - m); s += v[j]; }
    for (int off = 32; off; off >>= 1) s += __shfl_xor(s, off);
    float inv = 1.0f / s;
    u16* pp = P + (size_t)row * Q_LEN;
    #pragma unroll
    for (int j = 0; j < 8; ++j) pp[j * 64 + lane] = f2bf(v[j] * inv);
    if (lane == 0) mbuf[row] = m;
}

// ---------- b_att[b,c] = softmax_c(rowmax + rowterm) ----------
__global__ __launch_bounds__(256) void batt_kernel(const float* __restrict__ mbuf,
                                                   const float* __restrict__ rowterm,
                                                   float* __restrict__ batt) {
    __shared__ float red[8];
    int b = blockIdx.x;
    int tid = threadIdx.x;
    const float* mb = mbuf + (size_t)b * C_LEN;
    const float* rt = rowterm + (size_t)b * C_LEN;
    float v[8];
    float m = -1e30f;
    #pragma unroll
    for (int j = 0; j < 8; ++j) { int idx = j * 256 + tid; v[j] = mb[idx] + rt[idx]; m = fmaxf(m, v[j]); }
    for (int off = 32; off; off >>= 1) m = fmaxf(m, __shfl_xor(m, off));
    int wave = tid >> 6, lane = tid & 63;
    if (lane == 0) red[wave] = m;
    __syncthreads();
    m = fmaxf(fmaxf(red[0], red[1]), fmaxf(red[2], red[3]));
    float s = 0.f;
    #pragma unroll
    for (int j = 0; j < 8; ++j) { v[j] = __expf(v[j] - m); s += v[j]; }
    for (int off = 32; off; off >>= 1) s += __shfl_xor(s, off);
    if (lane == 0) red[4 + wave] = s;
    __syncthreads();
    s = red[4] + red[5] + red[6] + red[7];
    float inv = 1.0f / s;
    float* bb = batt + (size_t)b * C_LEN;
    #pragma unroll
    for (int j = 0; j < 8; ++j) bb[j * 256 + tid] = v[j] * inv;
}

// ---------- q2c[b,d] = sum_c b_att[b,c] * cbf[b,c,d] (chunked + atomic) ----------
__global__ __launch_bounds__(256) void q2c_kernel(const float* __restrict__ batt,
                                                  const u16* __restrict__ cbf,
                                                  float* __restrict__ q2c) {
    int d  = blockIdx.x * 256 + threadIdx.x;
    int b  = blockIdx.y;
    int c0 = blockIdx.z * 256;
    const u16* cb = cbf + ((size_t)b * C_LEN + c0) * D_DIM + d;
    const float* bb = batt + (size_t)b * C_LEN + c0;
    float s = 0.f;
    #pragma unroll 4
    for (int i = 0; i < 256; ++i) s += bb[i] * bf2f(cb[(size_t)i * D_DIM]);
    atomicAdd(&q2c[(size_t)b * D_DIM + d], s);
}

// ---------- cc2q = bf16(cbf * c2q) ----------
__global__ __launch_bounds__(256) void cc2q_kernel(const u16* __restrict__ cbf, const u16* __restrict__ c2q,
                                                   u16* __restrict__ cc2q) {
    int i = (blockIdx.x * 256 + threadIdx.x) * 4;
    u16x4 a = *(const u16x4*)(cbf + i);
    u16x4 c = *(const u16x4*)(c2q + i);
    u16x4 o;
    #pragma unroll
    for (int e = 0; e < 4; ++e) o[e] = f2bf(bf2f(a[e]) * bf2f(c[e]));
    *(u16x4*)(cc2q + i) = o;
}

// ---------- Wm[b,n,k] = bf16(W_l[n,k] + W_l[n,3072+k] * q2c[b,k]) ----------
__global__ __launch_bounds__(256) void wmerge_kernel(const float* __restrict__ W, const float* __restrict__ q2c,
                                                     u16* __restrict__ Wm) {
    int b = blockIdx.y;
    int i = (blockIdx.x * 256 + threadIdx.x) * 4;   // [0, 1M)
    int n = i >> 10, k = i & 1023;
    floatx4 w1 = *(const floatx4*)(W + (size_t)n * K4 + k);
    floatx4 w4 = *(const floatx4*)(W + (size_t)n * K4 + 3072 + k);
    floatx4 g  = *(const floatx4*)(q2c + (size_t)b * D_DIM + k);
    u16x4 o;
    #pragma unroll
    for (int e = 0; e < 4; ++e) o[e] = f2bf(w1[e] + w4[e] * g[e]);
    *(u16x4*)(Wm + (size_t)b * 1048576 + i) = o;
}

extern "C" void kernel_launch(void* const* d_in, const int* in_sizes, int n_in,
                              void* d_out, int out_size, void* d_ws, size_t ws_size,
                              hipStream_t stream) {
    const float* c   = (const float*)d_in[0];
    const float* q   = (const float*)d_in[1];
    const float* wcq = (const float*)d_in[2];
    // b_cq (d_in[3]), b_c (d_in[5]), b_q (d_in[7]) cancel in both softmaxes — unused.
    const float* w_c = (const float*)d_in[4];
    const float* w_q = (const float*)d_in[6];
    const float* W_l = (const float*)d_in[8];
    const float* b_l = (const float*)d_in[9];
    float* out = (float*)d_out;

    char* ws = (char*)d_ws;
    u16*   cbf     = (u16*)ws;                        // 32 MB @ 0
    float* S       = (float*)(ws + 33554432);         // 32 MB fp32 @ 32M
    u16*   c2q     = (u16*)(ws + 33554432);           // aliases S (bf16, 32 MB) after softmax
    u16*   qwbf    = (u16*)(ws + 67108864);           //  8 MB @ 64M
    u16*   qT      = (u16*)(ws + 75497472);           //  8 MB @ 72M
    u16*   P       = (u16*)(ws + 83886080);           // 16 MB @ 80M
    u16*   cc2q    = (u16*)(ws + 67108864);           // 32 MB, aliases qwbf+qT+P (all dead by then)
    u16*   Wbf     = (u16*)(ws + 100663296);          //  8 MB @ 96M (only cols 1024:3072 written/read)
    u16*   Wm      = (u16*)(ws + 109051904);          // 16 MB @ 104M
    float* rowterm = (float*)(ws + 125829120);        // 64 KB
    float* colterm = (float*)(ws + 125894656);        // 16 KB
    float* mbuf    = (float*)(ws + 125911040);        // 64 KB
    float* batt    = (float*)(ws + 125976576);        // 64 KB
    float* q2c     = (float*)(ws + 126042112);        // 32 KB   (total ~120.3 MB)

    hipMemsetAsync(q2c, 0, B_SZ * D_DIM * sizeof(float), stream);
    precast_c<<<dim3(4096), dim3(256), 0, stream>>>(c, w_c, cbf, rowterm);
    precast_q<<<dim3(1024), dim3(256), 0, stream>>>(q, wcq, w_q, qwbf, colterm);
    transpose_q_kernel<<<dim3(16, 32, 8), dim3(32, 8), 0, stream>>>(q, qT);
    precast_W<<<dim3(2048), dim3(256), 0, stream>>>(W_l, Wbf);
    gemm_async<0><<<dim3(4, 16, 8), dim3(256), 0, stream>>>(cbf, nullptr, nullptr, qwbf, nullptr, S, nullptr, nullptr);
    softmax_kernel<<<dim3(4096), dim3(256), 0, stream>>>(S, colterm, P, mbuf);
    batt_kernel<<<dim3(8), dim3(256), 0, stream>>>(mbuf, rowterm, batt);
    q2c_kernel<<<dim3(4, 8, 8), dim3(256), 0, stream>>>(batt, cbf, q2c);
    gemm_async<1><<<dim3(8, 16, 8), dim3(256), 0, stream>>>(P, nullptr, nullptr, qT, nullptr, nullptr, c2q, nullptr);
    cc2q_kernel<<<dim3(16384), dim3(256), 0, stream>>>(cbf, c2q, cc2q);
    wmerge_kernel<<<dim3(1024, 8), dim3(256), 0, stream>>>(W_l, q2c, Wm);
    gemm_async<2><<<dim3(8, 16, 8), dim3(256), 0, stream>>>(cbf, c2q, cc2q, Wm, Wbf, out, nullptr, b_l);
}

// Round 4
// 397.150 us; speedup vs baseline: 1.7903x; 1.0983x over previous
//
#include <hip/hip_runtime.h>

typedef unsigned short u16;
typedef __attribute__((ext_vector_type(4))) float floatx4;
typedef __attribute__((ext_vector_type(4))) unsigned short u16x4;
typedef __attribute__((ext_vector_type(8))) short short8;
typedef __attribute__((ext_vector_type(8))) __bf16 bf16x8;

#define B_SZ 8
#define C_LEN 2048
#define Q_LEN 512
#define D_DIM 1024
#define K4 (4 * D_DIM)

static __device__ __forceinline__ u16 f2bf(float f) {
    union { float f; unsigned int u; } v; v.f = f;
    unsigned int r = v.u + 0x7FFFu + ((v.u >> 16) & 1u);  // round-to-nearest-even
    return (u16)(r >> 16);
}
static __device__ __forceinline__ float bf2f(u16 h) {
    union { unsigned int u; float f; } v; v.u = ((unsigned int)h) << 16;
    return v.f;
}

// async global->LDS, 16B per lane; LDS dest = wave-uniform base + lane*16
static __device__ __forceinline__ void async16(const void* g, void* l) {
    __builtin_amdgcn_global_load_lds(
        (const __attribute__((address_space(1))) unsigned int*)g,
        (__attribute__((address_space(3))) unsigned int*)(unsigned int)(unsigned long long)l,
        16, 0, 0);
}

// ---------- cbf = bf16(c); rowterm[b,c] = c . w_c ----------
__global__ __launch_bounds__(256) void precast_c(const float* __restrict__ c, const float* __restrict__ w_c,
                                                 u16* __restrict__ cbf, float* __restrict__ rowterm) {
    int row = blockIdx.x * 4 + (threadIdx.x >> 6);
    int lane = threadIdx.x & 63;
    const float* src = c + (size_t)row * D_DIM;
    u16* dst = cbf + (size_t)row * D_DIM;
    float s = 0.f;
    #pragma unroll
    for (int j = 0; j < 4; ++j) {
        int idx = j * 256 + lane * 4;
        floatx4 a = *(const floatx4*)(src + idx);
        floatx4 w = *(const floatx4*)(w_c + idx);
        s += a[0]*w[0] + a[1]*w[1] + a[2]*w[2] + a[3]*w[3];
        u16x4 o;
        #pragma unroll
        for (int e = 0; e < 4; ++e) o[e] = f2bf(a[e]);
        *(u16x4*)(dst + idx) = o;
    }
    for (int off = 32; off; off >>= 1) s += __shfl_down(s, off);
    if (lane == 0) rowterm[row] = s;
}

// ---------- qwbf = bf16(q .* w_cq); colterm[b,q] = q . w_q ----------
__global__ __launch_bounds__(256) void precast_q(const float* __restrict__ q, const float* __restrict__ w_cq,
                                                 const float* __restrict__ w_q,
                                                 u16* __restrict__ qwbf, float* __restrict__ colterm) {
    int row = blockIdx.x * 4 + (threadIdx.x >> 6);
    int lane = threadIdx.x & 63;
    const float* src = q + (size_t)row * D_DIM;
    u16* dst = qwbf + (size_t)row * D_DIM;
    float s = 0.f;
    #pragma unroll
    for (int j = 0; j < 4; ++j) {
        int idx = j * 256 + lane * 4;
        floatx4 a  = *(const floatx4*)(src + idx);
        floatx4 wc = *(const floatx4*)(w_cq + idx);
        floatx4 wq = *(const floatx4*)(w_q + idx);
        s += a[0]*wq[0] + a[1]*wq[1] + a[2]*wq[2] + a[3]*wq[3];
        u16x4 o;
        #pragma unroll
        for (int e = 0; e < 4; ++e) o[e] = f2bf(a[e] * wc[e]);
        *(u16x4*)(dst + idx) = o;
    }
    for (int off = 32; off; off >>= 1) s += __shfl_down(s, off);
    if (lane == 0) colterm[row] = s;
}

// ---------- Wbf compact: Wbf[n][kk] = bf16(W_l[n, 1024+kk]), kk in [0,2048) ----------
__global__ __launch_bounds__(256) void precast_W(const float* __restrict__ W, u16* __restrict__ Wbf) {
    int t = blockIdx.x * 256 + threadIdx.x;
    int e4 = t * 4;                    // [0, 2M)
    int n = e4 >> 11;                  // row
    int kk = e4 & 2047;
    floatx4 v = *(const floatx4*)(W + (size_t)n * K4 + 1024 + kk);
    u16x4 o;
    #pragma unroll
    for (int e = 0; e < 4; ++e) o[e] = f2bf(v[e]);
    *(u16x4*)(Wbf + (size_t)n * 2048 + kk) = o;
}

// ---------- qT[b,d,q] = bf16(q[b,q,d]) ----------
__global__ void transpose_q_kernel(const float* __restrict__ q, u16* __restrict__ qT) {
    __shared__ float tile[32][33];
    int b = blockIdx.z;
    int q0 = blockIdx.x * 32;
    int d0 = blockIdx.y * 32;
    int tx = threadIdx.x, ty = threadIdx.y;  // 32 x 8
    const float* qb = q + (size_t)b * Q_LEN * D_DIM;
    #pragma unroll
    for (int j = 0; j < 4; ++j) {
        int row = ty + j * 8;
        tile[row][tx] = qb[(size_t)(q0 + row) * D_DIM + d0 + tx];
    }
    __syncthreads();
    u16* qTb = qT + (size_t)b * D_DIM * Q_LEN;
    #pragma unroll
    for (int j = 0; j < 4; ++j) {
        int row = ty + j * 8;
        qTb[(size_t)(d0 + row) * Q_LEN + q0 + tx] = f2bf(tile[tx][row]);
    }
}

// ---------- unified async bf16 GEMM, C = A @ B^T, 128x128 tile, BK=64, swizzled LDS ----------
// LDS layout: tile [128 rows][8 chunks of 16B]; logical chunk cb stored at phys cb^(row&7).
// MODE 0: S   = cbf @ qwbf^T                 out fp32 [2048,512]
// MODE 1: CC  = {P @ qT^T, cbf * that}       out bf16 interleaved [2048][2][1024]
// MODE 2: z   = cbf@Wm^T + CC0@W2^T + CC1@W3^T + b_l
template<int MODE>
__global__ __launch_bounds__(256) void gemm_async(
    const u16* __restrict__ A0, const u16* __restrict__ A1, const u16* __restrict__ A2,
    const u16* __restrict__ B0, const u16* __restrict__ B1,
    float* __restrict__ of, u16* __restrict__ ob, const float* __restrict__ bias) {
    constexpr int NSEC = (MODE == 2) ? 3 : 1;
    constexpr int KSEC = (MODE == 1) ? 512 : 1024;
    constexpr int LDO  = (MODE == 0) ? 512 : 1024;
    __shared__ u16 As[128 * 64];
    __shared__ u16 Bs[128 * 64];
    const int tid  = threadIdx.x;
    const int lane = tid & 63;
    const int wave = tid >> 6;
    const int b    = blockIdx.z;
    const int n0   = blockIdx.x * 128;
    const int m0   = blockIdx.y * 128;

    const u16* Aarr[NSEC];
    const u16* Barr[NSEC];
    int lda_[NSEC], ldb_[NSEC];
    if constexpr (MODE == 0) {
        Aarr[0] = A0 + (size_t)b * C_LEN * D_DIM; lda_[0] = 1024;
        Barr[0] = B0 + (size_t)b * Q_LEN * D_DIM; ldb_[0] = 1024;
    } else if constexpr (MODE == 1) {
        Aarr[0] = A0 + (size_t)b * C_LEN * Q_LEN; lda_[0] = 512;
        Barr[0] = B0 + (size_t)b * D_DIM * Q_LEN; ldb_[0] = 512;
    } else {
        Aarr[0] = A0 + (size_t)b * C_LEN * D_DIM;  lda_[0] = 1024;
        Barr[0] = B0 + (size_t)b * D_DIM * D_DIM;  ldb_[0] = 1024;   // Wm (per-batch)
        Aarr[1] = A1 + (size_t)b * C_LEN * 2048;        lda_[1] = 2048;  // CC + 0
        Barr[1] = B1;                                   ldb_[1] = 2048;  // Wbf + 0
        Aarr[2] = A1 + (size_t)b * C_LEN * 2048 + 1024; lda_[2] = 2048;  // CC + 1024
        Barr[2] = B1 + 1024;                            ldb_[2] = 2048;  // Wbf + 1024
    }

    // staging geometry: 16 chunks of 8 rows; wave w stages chunks 4w..4w+3
    const int srow = lane >> 3;                    // 0..7 row-within-chunk
    const int ssc  = ((lane & 7) ^ srow) * 8;      // swizzled source column (u16)

    floatx4 acc[4][4];
    #pragma unroll
    for (int i = 0; i < 4; ++i)
        #pragma unroll
        for (int j = 0; j < 4; ++j)
            acc[i][j] = (floatx4)(0.0f);

    const int wrow = (wave >> 1) * 64;
    const int wcol = (wave & 1) * 64;
    const int quad = lane >> 4;
    const int lrow = lane & 15;
    const int sw7  = lane & 7;                     // row&7 for all reader rows

    #pragma unroll
    for (int sec = 0; sec < NSEC; ++sec) {
        const u16* __restrict__ Ab = Aarr[sec];
        const u16* __restrict__ Bb = Barr[sec];
        const int LA = lda_[sec];
        const int LB = ldb_[sec];
        for (int k0 = 0; k0 < KSEC; k0 += 64) {
            #pragma unroll
            for (int cc = 0; cc < 4; ++cc) {
                int ch = wave * 4 + cc;
                int rr = ch * 8 + srow;
                async16(Ab + (size_t)(m0 + rr) * LA + k0 + ssc, &As[ch * 512]);
            }
            #pragma unroll
            for (int cc = 0; cc < 4; ++cc) {
                int ch = wave * 4 + cc;
                int rr = ch * 8 + srow;
                async16(Bb + (size_t)(n0 + rr) * LB + k0 + ssc, &Bs[ch * 512]);
            }
            __syncthreads();
            #pragma unroll
            for (int h = 0; h < 2; ++h) {
                const int pc = ((h * 4 + quad) ^ sw7) * 8;   // physical column (u16)
                bf16x8 af[4], bfr[4];
                #pragma unroll
                for (int i = 0; i < 4; ++i)
                    af[i] = __builtin_bit_cast(bf16x8, *(const short8*)&As[(wrow + i*16 + lrow) * 64 + pc]);
                #pragma unroll
                for (int j = 0; j < 4; ++j)
                    bfr[j] = __builtin_bit_cast(bf16x8, *(const short8*)&Bs[(wcol + j*16 + lrow) * 64 + pc]);
                #pragma unroll
                for (int i = 0; i < 4; ++i)
                    #pragma unroll
                    for (int j = 0; j < 4; ++j)
                        acc[i][j] = __builtin_amdgcn_mfma_f32_16x16x32_bf16(af[i], bfr[j], acc[i][j], 0, 0, 0);
            }
            __syncthreads();
        }
    }

    // ---- epilogue; C/D layout: col = lane&15, row = quad*4 + reg ----
    float* ofb = nullptr; u16* ccb = nullptr; const u16* cbr = nullptr;
    if (MODE == 0)      ofb = of + (size_t)b * C_LEN * Q_LEN;
    else if (MODE == 1) { ccb = ob + (size_t)b * C_LEN * 2048; cbr = A1 + (size_t)b * C_LEN * D_DIM; }
    else                ofb = of + (size_t)b * C_LEN * D_DIM;
    #pragma unroll
    for (int i = 0; i < 4; ++i) {
        #pragma unroll
        for (int j = 0; j < 4; ++j) {
            #pragma unroll
            for (int e = 0; e < 4; ++e) {
                int gm = m0 + wrow + i * 16 + quad * 4 + e;
                int gn = n0 + wcol + j * 16 + lrow;
                float v = acc[i][j][e];
                if (MODE == 0)      ofb[(size_t)gm * LDO + gn] = v;
                else if (MODE == 1) {
                    u16 p = f2bf(v);
                    float cv = bf2f(cbr[(size_t)gm * 1024 + gn]);
                    ccb[(size_t)gm * 2048 + gn]        = p;
                    ccb[(size_t)gm * 2048 + 1024 + gn] = f2bf(cv * bf2f(p));
                }
                else                ofb[(size_t)gm * LDO + gn] = v + bias[gn];
            }
        }
    }
}

// ---------- softmax over Q per (b,c) row; also record rowmax ----------
__global__ void softmax_kernel(const float* __restrict__ S, const float* __restrict__ colterm,
                               u16* __restrict__ P, float* __restrict__ mbuf) {
    int row = blockIdx.x * 4 + (threadIdx.x >> 6);
    int lane = threadIdx.x & 63;
    int b = row >> 11;  // C_LEN = 2048
    const float* sp = S + (size_t)row * Q_LEN;
    const float* cp = colterm + (size_t)b * Q_LEN;
    float v[8];
    float m = -1e30f;
    #pragma unroll
    for (int j = 0; j < 8; ++j) {
        int idx = j * 64 + lane;
        v[j] = sp[idx] + cp[idx];
        m = fmaxf(m, v[j]);
    }
    for (int off = 32; off; off >>= 1) m = fmaxf(m, __shfl_xor(m, off));
    float s = 0.f;
    #pragma unroll
    for (int j = 0; j < 8; ++j) { v[j] = __expf(v[j] - m); s += v[j]; }
    for (int off = 32; off; off >>= 1) s += __shfl_xor(s, off);
    float inv = 1.0f / s;
    u16* pp = P + (size_t)row * Q_LEN;
    #pragma unroll
    for (int j = 0; j < 8; ++j) pp[j * 64 + lane] = f2bf(v[j] * inv);
    if (lane == 0) mbuf[row] = m;
}

// ---------- b_att[b,c] = softmax_c(rowmax + rowterm) ----------
__global__ __launch_bounds__(256) void batt_kernel(const float* __restrict__ mbuf,
                                                   const float* __restrict__ rowterm,
                                                   float* __restrict__ batt) {
    __shared__ float red[8];
    int b = blockIdx.x;
    int tid = threadIdx.x;
    const float* mb = mbuf + (size_t)b * C_LEN;
    const float* rt = rowterm + (size_t)b * C_LEN;
    float v[8];
    float m = -1e30f;
    #pragma unroll
    for (int j = 0; j < 8; ++j) { int idx = j * 256 + tid; v[j] = mb[idx] + rt[idx]; m = fmaxf(m, v[j]); }
    for (int off = 32; off; off >>= 1) m = fmaxf(m, __shfl_xor(m, off));
    int wave = tid >> 6, lane = tid & 63;
    if (lane == 0) red[wave] = m;
    __syncthreads();
    m = fmaxf(fmaxf(red[0], red[1]), fmaxf(red[2], red[3]));
    float s = 0.f;
    #pragma unroll
    for (int j = 0; j < 8; ++j) { v[j] = __expf(v[j] - m); s += v[j]; }
    for (int off = 32; off; off >>= 1) s += __shfl_xor(s, off);
    if (lane == 0) red[4 + wave] = s;
    __syncthreads();
    s = red[4] + red[5] + red[6] + red[7];
    float inv = 1.0f / s;
    float* bb = batt + (size_t)b * C_LEN;
    #pragma unroll
    for (int j = 0; j < 8; ++j) bb[j * 256 + tid] = v[j] * inv;
}

// ---------- q2c[b,d] = sum_c b_att[b,c] * cbf[b,c,d] (chunked + atomic) ----------
__global__ __launch_bounds__(256) void q2c_kernel(const float* __restrict__ batt,
                                                  const u16* __restrict__ cbf,
                                                  float* __restrict__ q2c) {
    int d  = blockIdx.x * 256 + threadIdx.x;
    int b  = blockIdx.y;
    int c0 = blockIdx.z * 256;
    const u16* cb = cbf + ((size_t)b * C_LEN + c0) * D_DIM + d;
    const float* bb = batt + (size_t)b * C_LEN + c0;
    float s = 0.f;
    #pragma unroll 4
    for (int i = 0; i < 256; ++i) s += bb[i] * bf2f(cb[(size_t)i * D_DIM]);
    atomicAdd(&q2c[(size_t)b * D_DIM + d], s);
}

// ---------- Wm[b,n,k] = bf16(W_l[n,k] + W_l[n,3072+k] * q2c[b,k]) ----------
__global__ __launch_bounds__(256) void wmerge_kernel(const float* __restrict__ W, const float* __restrict__ q2c,
                                                     u16* __restrict__ Wm) {
    int b = blockIdx.y;
    int i = (blockIdx.x * 256 + threadIdx.x) * 4;   // [0, 1M)
    int n = i >> 10, k = i & 1023;
    floatx4 w1 = *(const floatx4*)(W + (size_t)n * K4 + k);
    floatx4 w4 = *(const floatx4*)(W + (size_t)n * K4 + 3072 + k);
    floatx4 g  = *(const floatx4*)(q2c + (size_t)b * D_DIM + k);
    u16x4 o;
    #pragma unroll
    for (int e = 0; e < 4; ++e) o[e] = f2bf(w1[e] + w4[e] * g[e]);
    *(u16x4*)(Wm + (size_t)b * 1048576 + i) = o;
}

extern "C" void kernel_launch(void* const* d_in, const int* in_sizes, int n_in,
                              void* d_out, int out_size, void* d_ws, size_t ws_size,
                              hipStream_t stream) {
    const float* c   = (const float*)d_in[0];
    const float* q   = (const float*)d_in[1];
    const float* wcq = (const float*)d_in[2];
    // b_cq (d_in[3]), b_c (d_in[5]), b_q (d_in[7]) cancel in both softmaxes — unused.
    const float* w_c = (const float*)d_in[4];
    const float* w_q = (const float*)d_in[6];
    const float* W_l = (const float*)d_in[8];
    const float* b_l = (const float*)d_in[9];
    float* out = (float*)d_out;

    char* ws = (char*)d_ws;
    // Region plan (MiB), lifetime-safe re-use:
    //   [0,32)    cbf                       (precast_c .. gemm<2>)
    //   [32,96)   CC interleaved c2q|cc2q   (written gemm<1>, read gemm<2>)
    //             before gemm<1>: S fp32 @32..64, qwbf @64..72
    //   [96,112)  P bf16 (softmax..gemm<1>), then Wm (wmerge..gemm<2>)
    //   [112,120) qT (transpose..gemm<1>), then Wbf compact 4MiB (precast_W..gemm<2>)
    //   [120,...) smalls
    u16*   cbf     = (u16*)ws;
    float* S       = (float*)(ws + 33554432);
    u16*   CC      = (u16*)(ws + 33554432);
    u16*   qwbf    = (u16*)(ws + 67108864);
    u16*   P       = (u16*)(ws + 100663296);
    u16*   Wm      = (u16*)(ws + 100663296);
    u16*   qT      = (u16*)(ws + 117440512);
    u16*   Wbf     = (u16*)(ws + 117440512);
    float* rowterm = (float*)(ws + 125829120);
    float* colterm = (float*)(ws + 125894656);
    float* mbuf    = (float*)(ws + 125911040);
    float* batt    = (float*)(ws + 125976576);
    float* q2c     = (float*)(ws + 126042112);   // total ~120.3 MiB

    hipMemsetAsync(q2c, 0, B_SZ * D_DIM * sizeof(float), stream);
    precast_c<<<dim3(4096), dim3(256), 0, stream>>>(c, w_c, cbf, rowterm);
    precast_q<<<dim3(1024), dim3(256), 0, stream>>>(q, wcq, w_q, qwbf, colterm);
    transpose_q_kernel<<<dim3(16, 32, 8), dim3(32, 8), 0, stream>>>(q, qT);
    gemm_async<0><<<dim3(4, 16, 8), dim3(256), 0, stream>>>(cbf, nullptr, nullptr, qwbf, nullptr, S, nullptr, nullptr);
    softmax_kernel<<<dim3(4096), dim3(256), 0, stream>>>(S, colterm, P, mbuf);
    batt_kernel<<<dim3(8), dim3(256), 0, stream>>>(mbuf, rowterm, batt);
    q2c_kernel<<<dim3(4, 8, 8), dim3(256), 0, stream>>>(batt, cbf, q2c);
    gemm_async<1><<<dim3(8, 16, 8), dim3(256), 0, stream>>>(P, cbf, nullptr, qT, nullptr, nullptr, CC, nullptr);
    wmerge_kernel<<<dim3(1024, 8), dim3(256), 0, stream>>>(W_l, q2c, Wm);
    precast_W<<<dim3(2048), dim3(256), 0, stream>>>(W_l, Wbf);
    gemm_async<2><<<dim3(8, 16, 8), dim3(256), 0, stream>>>(cbf, CC, nullptr, Wm, Wbf, out, nullptr, b_l);
}

// Round 5
// 364.826 us; speedup vs baseline: 1.9489x; 1.0886x over previous
//
#include <hip/hip_runtime.h>

typedef unsigned short u16;
typedef __attribute__((ext_vector_type(4))) float floatx4;
typedef __attribute__((ext_vector_type(4))) unsigned short u16x4;
typedef __attribute__((ext_vector_type(8))) short short8;
typedef __attribute__((ext_vector_type(8))) __bf16 bf16x8;

#define B_SZ 8
#define C_LEN 2048
#define Q_LEN 512
#define D_DIM 1024
#define K4 (4 * D_DIM)

static __device__ __forceinline__ u16 f2bf(float f) {
    union { float f; unsigned int u; } v; v.f = f;
    unsigned int r = v.u + 0x7FFFu + ((v.u >> 16) & 1u);  // round-to-nearest-even
    return (u16)(r >> 16);
}
static __device__ __forceinline__ float bf2f(u16 h) {
    union { unsigned int u; float f; } v; v.u = ((unsigned int)h) << 16;
    return v.f;
}

// async global->LDS, 16B per lane; LDS dest = wave-uniform base + lane*16
static __device__ __forceinline__ void async16(const void* g, void* l) {
    __builtin_amdgcn_global_load_lds(
        (const __attribute__((address_space(1))) unsigned int*)g,
        (__attribute__((address_space(3))) unsigned int*)(unsigned int)(unsigned long long)l,
        16, 0, 0);
}

// ---------- fused prep: precast_c | precast_q | transpose_q | zero q2c ----------
__global__ __launch_bounds__(256) void prep_kernel(
    const float* __restrict__ c, const float* __restrict__ q,
    const float* __restrict__ w_cq, const float* __restrict__ w_c, const float* __restrict__ w_q,
    u16* __restrict__ cbf, u16* __restrict__ qwbf, u16* __restrict__ qT,
    float* __restrict__ rowterm, float* __restrict__ colterm, float* __restrict__ q2c) {
    int blk = blockIdx.x;
    int tid = threadIdx.x;
    if (blk < 4096) {
        // precast_c: cbf = bf16(c); rowterm = c . w_c
        int row = blk * 4 + (tid >> 6);
        int lane = tid & 63;
        const float* src = c + (size_t)row * D_DIM;
        u16* dst = cbf + (size_t)row * D_DIM;
        float s = 0.f;
        #pragma unroll
        for (int j = 0; j < 4; ++j) {
            int idx = j * 256 + lane * 4;
            floatx4 a = *(const floatx4*)(src + idx);
            floatx4 w = *(const floatx4*)(w_c + idx);
            s += a[0]*w[0] + a[1]*w[1] + a[2]*w[2] + a[3]*w[3];
            u16x4 o;
            #pragma unroll
            for (int e = 0; e < 4; ++e) o[e] = f2bf(a[e]);
            *(u16x4*)(dst + idx) = o;
        }
        for (int off = 32; off; off >>= 1) s += __shfl_down(s, off);
        if (lane == 0) rowterm[row] = s;
    } else if (blk < 5120) {
        // precast_q: qwbf = bf16(q .* w_cq); colterm = q . w_q
        int row = (blk - 4096) * 4 + (tid >> 6);
        int lane = tid & 63;
        const float* src = q + (size_t)row * D_DIM;
        u16* dst = qwbf + (size_t)row * D_DIM;
        float s = 0.f;
        #pragma unroll
        for (int j = 0; j < 4; ++j) {
            int idx = j * 256 + lane * 4;
            floatx4 a  = *(const floatx4*)(src + idx);
            floatx4 wc = *(const floatx4*)(w_cq + idx);
            floatx4 wq = *(const floatx4*)(w_q + idx);
            s += a[0]*wq[0] + a[1]*wq[1] + a[2]*wq[2] + a[3]*wq[3];
            u16x4 o;
            #pragma unroll
            for (int e = 0; e < 4; ++e) o[e] = f2bf(a[e] * wc[e]);
            *(u16x4*)(dst + idx) = o;
        }
        for (int off = 32; off; off >>= 1) s += __shfl_down(s, off);
        if (lane == 0) colterm[row] = s;
    } else if (blk < 9216) {
        // transpose_q: qT[b,d,q] = bf16(q[b,q,d])
        __shared__ float tile[32][33];
        int t = blk - 5120;
        int q0 = (t & 15) * 32;
        int d0 = ((t >> 4) & 31) * 32;
        int b = t >> 9;
        int tx = tid & 31, ty = tid >> 5;  // 32 x 8
        const float* qb = q + (size_t)b * Q_LEN * D_DIM;
        #pragma unroll
        for (int j = 0; j < 4; ++j) {
            int row = ty + j * 8;
            tile[row][tx] = qb[(size_t)(q0 + row) * D_DIM + d0 + tx];
        }
        __syncthreads();
        u16* qTb = qT + (size_t)b * D_DIM * Q_LEN;
        #pragma unroll
        for (int j = 0; j < 4; ++j) {
            int row = ty + j * 8;
            qTb[(size_t)(d0 + row) * Q_LEN + q0 + tx] = f2bf(tile[tx][row]);
        }
    } else {
        // zero q2c (8192 floats)
        int i = (blk - 9216) * 256 + tid;
        q2c[i] = 0.0f;
    }
}

// ---------- fused W prep: Wm[b,n,k] = bf16(W1 + W4*q2c); Wbf[n,kk] = bf16(W[n,1024+kk]) ----------
__global__ __launch_bounds__(256) void wmerge_all(const float* __restrict__ W, const float* __restrict__ q2c,
                                                  u16* __restrict__ Wm, u16* __restrict__ Wbf) {
    int n = blockIdx.x;             // 1024 rows
    int k = threadIdx.x * 4;        // 0..1023
    const float* wr = W + (size_t)n * K4;
    floatx4 w1 = *(const floatx4*)(wr + k);
    floatx4 w4 = *(const floatx4*)(wr + 3072 + k);
    #pragma unroll
    for (int p = 0; p < 2; ++p) {
        int kk = p * 1024 + k;
        floatx4 v = *(const floatx4*)(wr + 1024 + kk);
        u16x4 o;
        #pragma unroll
        for (int e = 0; e < 4; ++e) o[e] = f2bf(v[e]);
        *(u16x4*)(Wbf + (size_t)n * 2048 + kk) = o;
    }
    #pragma unroll
    for (int b = 0; b < 8; ++b) {
        floatx4 g = *(const floatx4*)(q2c + (size_t)b * D_DIM + k);
        u16x4 o;
        #pragma unroll
        for (int e = 0; e < 4; ++e) o[e] = f2bf(w1[e] + w4[e] * g[e]);
        *(u16x4*)(Wm + (size_t)b * 1048576 + (size_t)n * 1024 + k) = o;
    }
}

// ---------- unified async bf16 GEMM, C = A @ B^T, 128x128 tile, BK=64, swizzled LDS ----------
// 1-D grid, XCD-pinned: b = lin & 7 (dispatch round-robins linear id over 8 XCDs).
// LDS layout: tile [128 rows][8 chunks of 16B]; logical chunk cb stored at phys cb^(row&7).
// MODE 0: S   = cbf @ qwbf^T                 out fp32 [2048,512]
// MODE 1: CC  = {P @ qT^T, cbf * that}       out bf16 interleaved [2048][2][1024]
// MODE 2: z   = cbf@Wm^T + CC0@W2^T + CC1@W3^T + b_l
template<int MODE>
__global__ __launch_bounds__(256) void gemm_async(
    const u16* __restrict__ A0, const u16* __restrict__ A1, const u16* __restrict__ A2,
    const u16* __restrict__ B0, const u16* __restrict__ B1,
    float* __restrict__ of, u16* __restrict__ ob, const float* __restrict__ bias) {
    constexpr int NSEC = (MODE == 2) ? 3 : 1;
    constexpr int KSEC = (MODE == 1) ? 512 : 1024;
    constexpr int LDO  = (MODE == 0) ? 512 : 1024;
    constexpr int NTILES = (MODE == 0) ? 4 : 8;
    __shared__ u16 As[128 * 64];
    __shared__ u16 Bs[128 * 64];
    const int tid  = threadIdx.x;
    const int lane = tid & 63;
    const int wave = tid >> 6;
    const int lin  = blockIdx.x;
    const int b    = lin & 7;            // XCD pin
    const int rem  = lin >> 3;
    const int n0   = (rem % NTILES) * 128;
    const int m0   = (rem / NTILES) * 128;

    const u16* Aarr[NSEC];
    const u16* Barr[NSEC];
    int lda_[NSEC], ldb_[NSEC];
    if constexpr (MODE == 0) {
        Aarr[0] = A0 + (size_t)b * C_LEN * D_DIM; lda_[0] = 1024;
        Barr[0] = B0 + (size_t)b * Q_LEN * D_DIM; ldb_[0] = 1024;
    } else if constexpr (MODE == 1) {
        Aarr[0] = A0 + (size_t)b * C_LEN * Q_LEN; lda_[0] = 512;
        Barr[0] = B0 + (size_t)b * D_DIM * Q_LEN; ldb_[0] = 512;
    } else {
        Aarr[0] = A0 + (size_t)b * C_LEN * D_DIM;  lda_[0] = 1024;
        Barr[0] = B0 + (size_t)b * D_DIM * D_DIM;  ldb_[0] = 1024;   // Wm (per-batch)
        Aarr[1] = A1 + (size_t)b * C_LEN * 2048;        lda_[1] = 2048;  // CC + 0
        Barr[1] = B1;                                   ldb_[1] = 2048;  // Wbf + 0
        Aarr[2] = A1 + (size_t)b * C_LEN * 2048 + 1024; lda_[2] = 2048;  // CC + 1024
        Barr[2] = B1 + 1024;                            ldb_[2] = 2048;  // Wbf + 1024
    }

    // staging geometry: 16 chunks of 8 rows; wave w stages chunks 4w..4w+3
    const int srow = lane >> 3;                    // 0..7 row-within-chunk
    const int ssc  = ((lane & 7) ^ srow) * 8;      // swizzled source column (u16)

    floatx4 acc[4][4];
    #pragma unroll
    for (int i = 0; i < 4; ++i)
        #pragma unroll
        for (int j = 0; j < 4; ++j)
            acc[i][j] = (floatx4)(0.0f);

    const int wrow = (wave >> 1) * 64;
    const int wcol = (wave & 1) * 64;
    const int quad = lane >> 4;
    const int lrow = lane & 15;
    const int sw7  = lane & 7;                     // row&7 for all reader rows

    #pragma unroll
    for (int sec = 0; sec < NSEC; ++sec) {
        const u16* __restrict__ Ab = Aarr[sec];
        const u16* __restrict__ Bb = Barr[sec];
        const int LA = lda_[sec];
        const int LB = ldb_[sec];
        for (int k0 = 0; k0 < KSEC; k0 += 64) {
            #pragma unroll
            for (int cc = 0; cc < 4; ++cc) {
                int ch = wave * 4 + cc;
                int rr = ch * 8 + srow;
                async16(Ab + (size_t)(m0 + rr) * LA + k0 + ssc, &As[ch * 512]);
            }
            #pragma unroll
            for (int cc = 0; cc < 4; ++cc) {
                int ch = wave * 4 + cc;
                int rr = ch * 8 + srow;
                async16(Bb + (size_t)(n0 + rr) * LB + k0 + ssc, &Bs[ch * 512]);
            }
            __syncthreads();
            #pragma unroll
            for (int h = 0; h < 2; ++h) {
                const int pc = ((h * 4 + quad) ^ sw7) * 8;   // physical column (u16)
                bf16x8 af[4], bfr[4];
                #pragma unroll
                for (int i = 0; i < 4; ++i)
                    af[i] = __builtin_bit_cast(bf16x8, *(const short8*)&As[(wrow + i*16 + lrow) * 64 + pc]);
                #pragma unroll
                for (int j = 0; j < 4; ++j)
                    bfr[j] = __builtin_bit_cast(bf16x8, *(const short8*)&Bs[(wcol + j*16 + lrow) * 64 + pc]);
                #pragma unroll
                for (int i = 0; i < 4; ++i)
                    #pragma unroll
                    for (int j = 0; j < 4; ++j)
                        acc[i][j] = __builtin_amdgcn_mfma_f32_16x16x32_bf16(af[i], bfr[j], acc[i][j], 0, 0, 0);
            }
            __syncthreads();
        }
    }

    // ---- epilogue; C/D layout: col = lane&15, row = quad*4 + reg ----
    float* ofb = nullptr; u16* ccb = nullptr; const u16* cbr = nullptr;
    if (MODE == 0)      ofb = of + (size_t)b * C_LEN * Q_LEN;
    else if (MODE == 1) { ccb = ob + (size_t)b * C_LEN * 2048; cbr = A1 + (size_t)b * C_LEN * D_DIM; }
    else                ofb = of + (size_t)b * C_LEN * D_DIM;
    #pragma unroll
    for (int i = 0; i < 4; ++i) {
        #pragma unroll
        for (int j = 0; j < 4; ++j) {
            #pragma unroll
            for (int e = 0; e < 4; ++e) {
                int gm = m0 + wrow + i * 16 + quad * 4 + e;
                int gn = n0 + wcol + j * 16 + lrow;
                float v = acc[i][j][e];
                if (MODE == 0)      ofb[(size_t)gm * LDO + gn] = v;
                else if (MODE == 1) {
                    u16 p = f2bf(v);
                    float cv = bf2f(cbr[(size_t)gm * 1024 + gn]);
                    ccb[(size_t)gm * 2048 + gn]        = p;
                    ccb[(size_t)gm * 2048 + 1024 + gn] = f2bf(cv * bf2f(p));
                }
                else                ofb[(size_t)gm * LDO + gn] = v + bias[gn];
            }
        }
    }
}

// ---------- softmax over Q per (b,c) row; also record rowmax ----------
__global__ void softmax_kernel(const float* __restrict__ S, const float* __restrict__ colterm,
                               u16* __restrict__ P, float* __restrict__ mbuf) {
    int row = blockIdx.x * 4 + (threadIdx.x >> 6);
    int lane = threadIdx.x & 63;
    int b = row >> 11;  // C_LEN = 2048
    const float* sp = S + (size_t)row * Q_LEN;
    const float* cp = colterm + (size_t)b * Q_LEN;
    float v[8];
    float m = -1e30f;
    #pragma unroll
    for (int j = 0; j < 8; ++j) {
        int idx = j * 64 + lane;
        v[j] = sp[idx] + cp[idx];
        m = fmaxf(m, v[j]);
    }
    for (int off = 32; off; off >>= 1) m = fmaxf(m, __shfl_xor(m, off));
    float s = 0.f;
    #pragma unroll
    for (int j = 0; j < 8; ++j) { v[j] = __expf(v[j] - m); s += v[j]; }
    for (int off = 32; off; off >>= 1) s += __shfl_xor(s, off);
    float inv = 1.0f / s;
    u16* pp = P + (size_t)row * Q_LEN;
    #pragma unroll
    for (int j = 0; j < 8; ++j) pp[j * 64 + lane] = f2bf(v[j] * inv);
    if (lane == 0) mbuf[row] = m;
}

// ---------- b_att[b,c] = softmax_c(rowmax + rowterm) ----------
__global__ __launch_bounds__(256) void batt_kernel(const float* __restrict__ mbuf,
                                                   const float* __restrict__ rowterm,
                                                   float* __restrict__ batt) {
    __shared__ float red[8];
    int b = blockIdx.x;
    int tid = threadIdx.x;
    const float* mb = mbuf + (size_t)b * C_LEN;
    const float* rt = rowterm + (size_t)b * C_LEN;
    float v[8];
    float m = -1e30f;
    #pragma unroll
    for (int j = 0; j < 8; ++j) { int idx = j * 256 + tid; v[j] = mb[idx] + rt[idx]; m = fmaxf(m, v[j]); }
    for (int off = 32; off; off >>= 1) m = fmaxf(m, __shfl_xor(m, off));
    int wave = tid >> 6, lane = tid & 63;
    if (lane == 0) red[wave] = m;
    __syncthreads();
    m = fmaxf(fmaxf(red[0], red[1]), fmaxf(red[2], red[3]));
    float s = 0.f;
    #pragma unroll
    for (int j = 0; j < 8; ++j) { v[j] = __expf(v[j] - m); s += v[j]; }
    for (int off = 32; off; off >>= 1) s += __shfl_xor(s, off);
    if (lane == 0) red[4 + wave] = s;
    __syncthreads();
    s = red[4] + red[5] + red[6] + red[7];
    float inv = 1.0f / s;
    float* bb = batt + (size_t)b * C_LEN;
    #pragma unroll
    for (int j = 0; j < 8; ++j) bb[j * 256 + tid] = v[j] * inv;
}

// ---------- q2c[b,d] = sum_c b_att[b,c] * cbf[b,c,d] (chunked + atomic) ----------
__global__ __launch_bounds__(256) void q2c_kernel(const float* __restrict__ batt,
                                                  const u16* __restrict__ cbf,
                                                  float* __restrict__ q2c) {
    int d  = blockIdx.x * 256 + threadIdx.x;
    int b  = blockIdx.y;
    int c0 = blockIdx.z * 256;
    const u16* cb = cbf + ((size_t)b * C_LEN + c0) * D_DIM + d;
    const float* bb = batt + (size_t)b * C_LEN + c0;
    float s = 0.f;
    #pragma unroll 4
    for (int i = 0; i < 256; ++i) s += bb[i] * bf2f(cb[(size_t)i * D_DIM]);
    atomicAdd(&q2c[(size_t)b * D_DIM + d], s);
}

extern "C" void kernel_launch(void* const* d_in, const int* in_sizes, int n_in,
                              void* d_out, int out_size, void* d_ws, size_t ws_size,
                              hipStream_t stream) {
    const float* c   = (const float*)d_in[0];
    const float* q   = (const float*)d_in[1];
    const float* wcq = (const float*)d_in[2];
    // b_cq (d_in[3]), b_c (d_in[5]), b_q (d_in[7]) cancel in both softmaxes — unused.
    const float* w_c = (const float*)d_in[4];
    const float* w_q = (const float*)d_in[6];
    const float* W_l = (const float*)d_in[8];
    const float* b_l = (const float*)d_in[9];
    float* out = (float*)d_out;

    char* ws = (char*)d_ws;
    // Region plan (MiB), lifetime-safe re-use:
    //   [0,32)    cbf                       (prep .. gemm<2>)
    //   [32,96)   CC interleaved c2q|cc2q   (written gemm<1>, read gemm<2>)
    //             before gemm<1>: S fp32 @32..64, qwbf @64..72
    //   [96,112)  P bf16 (softmax..gemm<1>), then Wm (wmerge_all..gemm<2>)
    //   [112,120) qT (prep..gemm<1>), then Wbf compact 4MiB (wmerge_all..gemm<2>)
    //   [120,...) smalls
    u16*   cbf     = (u16*)ws;
    float* S       = (float*)(ws + 33554432);
    u16*   CC      = (u16*)(ws + 33554432);
    u16*   qwbf    = (u16*)(ws + 67108864);
    u16*   P       = (u16*)(ws + 100663296);
    u16*   Wm      = (u16*)(ws + 100663296);
    u16*   qT      = (u16*)(ws + 117440512);
    u16*   Wbf     = (u16*)(ws + 117440512);
    float* rowterm = (float*)(ws + 125829120);
    float* colterm = (float*)(ws + 125894656);
    float* mbuf    = (float*)(ws + 125911040);
    float* batt    = (float*)(ws + 125976576);
    float* q2c     = (float*)(ws + 126042112);   // total ~120.3 MiB

    prep_kernel<<<dim3(9248), dim3(256), 0, stream>>>(c, q, wcq, w_c, w_q,
                                                      cbf, qwbf, qT, rowterm, colterm, q2c);
    gemm_async<0><<<dim3(512), dim3(256), 0, stream>>>(cbf, nullptr, nullptr, qwbf, nullptr, S, nullptr, nullptr);
    softmax_kernel<<<dim3(4096), dim3(256), 0, stream>>>(S, colterm, P, mbuf);
    batt_kernel<<<dim3(8), dim3(256), 0, stream>>>(mbuf, rowterm, batt);
    q2c_kernel<<<dim3(4, 8, 8), dim3(256), 0, stream>>>(batt, cbf, q2c);
    gemm_async<1><<<dim3(1024), dim3(256), 0, stream>>>(P, cbf, nullptr, qT, nullptr, nullptr, CC, nullptr);
    wmerge_all<<<dim3(1024), dim3(256), 0, stream>>>(W_l, q2c, Wm, Wbf);
    gemm_async<2><<<dim3(1024), dim3(256), 0, stream>>>(cbf, CC, nullptr, Wm, Wbf, out, nullptr, b_l);
}